// Round 1
// baseline (195.973 us; speedup 1.0000x reference)
//
#include <hip/hip_runtime.h>
#include <hip/hip_fp16.h>

// out = sa*sb * (x @ q_b) @ q_a^T + bias
// x: [8192][4096] f32, q_a: [4096][512] i32, q_b: [4096][512] i32
// GEMM1: t[8192][512] = x @ q_b           (fp16 MFMA, fp32 acc, t stored fp16)
// GEMM2: out[8192][4096] = t @ q_a^T      (fp16 MFMA, fp32 acc, scale+bias epilogue)

#define M_TOT 8192
#define N_OUT 4096
#define K_IN  4096
#define RANK  512

typedef _Float16 f16x8 __attribute__((ext_vector_type(8)));
typedef float f32x4 __attribute__((ext_vector_type(4)));

__device__ __forceinline__ void gload_lds16(const void* g, void* l) {
  __builtin_amdgcn_global_load_lds(
      (const __attribute__((address_space(1))) unsigned int*)g,
      (__attribute__((address_space(3))) unsigned int*)l, 16, 0, 0);
}

// ---- convert q_a int32 -> fp16, same [OUT][RANK] layout ----
__global__ void k_cvt_qa(const int4* __restrict__ q, ushort4* __restrict__ o, int n4) {
  int i = blockIdx.x * blockDim.x + threadIdx.x;
  if (i >= n4) return;
  int4 v = q[i];
  ushort4 r;
  r.x = __half_as_ushort(__float2half_rn((float)v.x));
  r.y = __half_as_ushort(__float2half_rn((float)v.y));
  r.z = __half_as_ushort(__float2half_rn((float)v.z));
  r.w = __half_as_ushort(__float2half_rn((float)v.w));
  o[i] = r;
}

// ---- transpose q_b [K_IN][RANK] i32 -> qbt [RANK][K_IN] fp16 ----
__global__ void k_transpose_qb(const int* __restrict__ qb, __half* __restrict__ qbt) {
  __shared__ __half tile[32][33];
  int tx = threadIdx.x & 31, ty = threadIdx.x >> 5;  // ty 0..7
  int k0 = blockIdx.x * 32, r0 = blockIdx.y * 32;
#pragma unroll
  for (int j = 0; j < 4; ++j) {
    int k = k0 + ty + j * 8;
    tile[ty + j * 8][tx] = __float2half_rn((float)qb[(size_t)k * RANK + r0 + tx]);
  }
  __syncthreads();
#pragma unroll
  for (int j = 0; j < 4; ++j) {
    int r = r0 + ty + j * 8;
    qbt[(size_t)r * K_IN + k0 + tx] = tile[tx][ty + j * 8];
  }
}

// ---- GEMM1: t = X @ qbt^T  (M=8192, N=RANK=512, K=4096), BM=128 BN=64 BK=32 ----
// 256 threads = 4 waves (2 m-halves x 2 n-halves), wave tile 64x32, acc[4][2]
__global__ __launch_bounds__(256, 2) void k_gemm1(
    const float* __restrict__ X, const __half* __restrict__ Bt,
    __half* __restrict__ T) {
  __shared__ __align__(16) __half As[128][32];
  __shared__ __align__(16) __half Bs[64][32];
  const int tid = threadIdx.x;
  const int lane = tid & 63;
  const int wid = tid >> 6;
  const int wm = wid & 1;
  const int wn = wid >> 1;
  const int m0 = blockIdx.x * 128;
  const int n0 = blockIdx.y * 64;

  f32x4 acc[4][2] = {};

  // A staging (fp32 -> fp16 in flight): thread covers row ar(+32*rr), 4 floats at ac
  const int ar = tid >> 3;         // 0..31
  const int ac = (tid & 7) * 4;    // 0..28
  const float* xbase = X + (size_t)(m0 + ar) * K_IN + ac;

  // B staging: global_load_lds, 1x16B per thread (tile 64x32 halfs = 4KB)
  const __half* bbase = Bt + (size_t)(n0 + (tid >> 2)) * K_IN + (tid & 3) * 8;
  char* blds = (char*)&Bs[0][0] + tid * 16;

  const int fr = lane & 15;
  const int ko = (lane >> 4) * 8;
  const int arow = wm * 64 + fr;
  const int brow = wn * 32 + fr;

  for (int k0 = 0; k0 < K_IN; k0 += 32) {
    gload_lds16(bbase + k0, blds);
#pragma unroll
    for (int rr = 0; rr < 4; ++rr) {
      float4 v = *(const float4*)(xbase + k0 + (size_t)rr * 32 * K_IN);
      union { __half2 h[2]; uint2 u; } p;
      p.h[0] = __floats2half2_rn(v.x, v.y);
      p.h[1] = __floats2half2_rn(v.z, v.w);
      *(uint2*)&As[ar + rr * 32][ac] = p.u;
    }
    __syncthreads();
    f16x8 a[4], b[2];
#pragma unroll
    for (int mi = 0; mi < 4; ++mi) a[mi] = *(const f16x8*)&As[arow + mi * 16][ko];
#pragma unroll
    for (int ni = 0; ni < 2; ++ni) b[ni] = *(const f16x8*)&Bs[brow + ni * 16][ko];
#pragma unroll
    for (int mi = 0; mi < 4; ++mi)
#pragma unroll
      for (int ni = 0; ni < 2; ++ni)
        acc[mi][ni] = __builtin_amdgcn_mfma_f32_16x16x32_f16(a[mi], b[ni], acc[mi][ni], 0, 0, 0);
    __syncthreads();
  }

#pragma unroll
  for (int mi = 0; mi < 4; ++mi)
#pragma unroll
    for (int ni = 0; ni < 2; ++ni) {
      int col = n0 + wn * 32 + ni * 16 + fr;
      int rbase = m0 + wm * 64 + mi * 16 + (lane >> 4) * 4;
#pragma unroll
      for (int j = 0; j < 4; ++j)
        T[(size_t)(rbase + j) * RANK + col] = __float2half_rn(acc[mi][ni][j]);
    }
}

// ---- GEMM2: out = t @ qa^T * scale + bias (M=8192, N=4096, K=512), 128x128x32 ----
// 256 threads = 4 waves (2x2), wave tile 64x64, acc[4][4]
__global__ __launch_bounds__(256, 2) void k_gemm2(
    const __half* __restrict__ T, const __half* __restrict__ QA,
    const float* __restrict__ sa, const float* __restrict__ sb,
    const float* __restrict__ bias, float* __restrict__ Out) {
  __shared__ __align__(16) __half As[128][32];
  __shared__ __align__(16) __half Bs[128][32];
  const int tid = threadIdx.x;
  const int lane = tid & 63;
  const int wid = tid >> 6;
  const int wm = wid & 1;
  const int wn = wid >> 1;
  const int m0 = blockIdx.x * 128;
  const int n0 = blockIdx.y * 128;

  f32x4 acc[4][4] = {};

  const int sr = tid >> 2;          // 0..63
  const int sch = (tid & 3) * 8;    // half offset
  const __half* abase0 = T  + (size_t)(m0 + sr) * RANK + sch;
  const __half* abase1 = T  + (size_t)(m0 + 64 + sr) * RANK + sch;
  const __half* bbase0 = QA + (size_t)(n0 + sr) * RANK + sch;
  const __half* bbase1 = QA + (size_t)(n0 + 64 + sr) * RANK + sch;
  char* alds0 = (char*)&As[0][0] + tid * 16;
  char* alds1 = (char*)&As[64][0] + tid * 16;
  char* blds0 = (char*)&Bs[0][0] + tid * 16;
  char* blds1 = (char*)&Bs[64][0] + tid * 16;

  const int fr = lane & 15;
  const int ko = (lane >> 4) * 8;
  const int arow = wm * 64 + fr;
  const int brow = wn * 64 + fr;

  for (int k0 = 0; k0 < RANK; k0 += 32) {
    gload_lds16(abase0 + k0, alds0);
    gload_lds16(abase1 + k0, alds1);
    gload_lds16(bbase0 + k0, blds0);
    gload_lds16(bbase1 + k0, blds1);
    __syncthreads();
    f16x8 a[4], b[4];
#pragma unroll
    for (int mi = 0; mi < 4; ++mi) a[mi] = *(const f16x8*)&As[arow + mi * 16][ko];
#pragma unroll
    for (int ni = 0; ni < 4; ++ni) b[ni] = *(const f16x8*)&Bs[brow + ni * 16][ko];
#pragma unroll
    for (int mi = 0; mi < 4; ++mi)
#pragma unroll
      for (int ni = 0; ni < 4; ++ni)
        acc[mi][ni] = __builtin_amdgcn_mfma_f32_16x16x32_f16(a[mi], b[ni], acc[mi][ni], 0, 0, 0);
    __syncthreads();
  }

  const float scale = sa[0] * sb[0];
#pragma unroll
  for (int mi = 0; mi < 4; ++mi)
#pragma unroll
    for (int ni = 0; ni < 4; ++ni) {
      int col = n0 + wn * 64 + ni * 16 + fr;
      float bv = bias[col];
      int rbase = m0 + wm * 64 + mi * 16 + (lane >> 4) * 4;
#pragma unroll
      for (int j = 0; j < 4; ++j)
        Out[(size_t)(rbase + j) * N_OUT + col] = acc[mi][ni][j] * scale + bv;
    }
}

extern "C" void kernel_launch(void* const* d_in, const int* in_sizes, int n_in,
                              void* d_out, int out_size, void* d_ws, size_t ws_size,
                              hipStream_t stream) {
  const float* x    = (const float*)d_in[0];
  const int*   qa   = (const int*)d_in[1];
  const int*   qb   = (const int*)d_in[2];
  const float* sa   = (const float*)d_in[3];
  const float* sb   = (const float*)d_in[4];
  const float* bias = (const float*)d_in[5];
  float* out = (float*)d_out;

  // workspace layout: qa_f16 4MB | qbt_f16 4MB | t_f16 8MB  (16MB total)
  char* ws = (char*)d_ws;
  __half* qa_h = (__half*)ws;
  __half* qbt  = (__half*)(ws + (4u << 20));
  __half* t    = (__half*)(ws + (8u << 20));

  // convert q_a: 2M elements / 4 per thread
  k_cvt_qa<<<2048, 256, 0, stream>>>((const int4*)qa, (ushort4*)qa_h, (N_OUT * RANK) / 4);
  // transpose+convert q_b -> [RANK][K_IN]
  dim3 tg(K_IN / 32, RANK / 32);
  k_transpose_qb<<<tg, 256, 0, stream>>>(qb, qbt);
  // GEMM1: t = x @ q_b
  dim3 g1(M_TOT / 128, RANK / 64);
  k_gemm1<<<g1, 256, 0, stream>>>(x, qbt, t);
  // GEMM2: out = t @ q_a^T * scale + bias
  dim3 g2(M_TOT / 128, N_OUT / 128);
  k_gemm2<<<g2, 256, 0, stream>>>(t, qa_h, sa, sb, bias, out);
}